// Round 6
// baseline (232.387 us; speedup 1.0000x reference)
//
#include <hip/hip_runtime.h>
#include <hip/hip_bf16.h>

#define NB 16
#define NS 2048
#define NE 256
#define NOUT 256
#define CAP 49152

typedef __attribute__((ext_vector_type(4))) float f32x4;
typedef __attribute__((ext_vector_type(8))) short s16x8;
typedef __attribute__((ext_vector_type(4))) short s16x4;
typedef unsigned int u32;
typedef unsigned long long u64;

__device__ __forceinline__ short bf16rn(float f) {
  unsigned u = __builtin_bit_cast(unsigned, f);
  u += 0x7FFFu + ((u >> 16) & 1u);
  return (short)(u >> 16);
}
__device__ __forceinline__ float bf16f(short s) {
  unsigned u = ((unsigned)(unsigned short)s) << 16;
  return __builtin_bit_cast(float, u);
}
__device__ __forceinline__ void gld_lds16(const void* g, void* l) {
  __builtin_amdgcn_global_load_lds(
      (const __attribute__((address_space(1))) u32*)g,
      (__attribute__((address_space(3))) u32*)l, 16, 0, 0);
}

// ---------- prep: x f32 -> xbf bf16 + sq (proven R2-R4) ----------
__global__ __launch_bounds__(256) void prep_kernel(const float* __restrict__ x,
                                                   short* __restrict__ xbf,
                                                   float* __restrict__ sq) {
  int row = blockIdx.x * 4 + (threadIdx.x >> 6);
  int lane = threadIdx.x & 63;
  f32x4 v = *(const f32x4*)(x + (size_t)row * NE + lane * 4);
  s16x4 p;
  p[0] = bf16rn(v.x); p[1] = bf16rn(v.y); p[2] = bf16rn(v.z); p[3] = bf16rn(v.w);
  *(s16x4*)(xbf + (size_t)row * NE + lane * 4) = p;
  float s = v.x * v.x + v.y * v.y + v.z * v.z + v.w * v.w;
#pragma unroll
  for (int off = 32; off; off >>= 1) s += __shfl_xor(s, off);
  if (lane == 0) sq[row] = s;
}

// one half-chunk (128 cols x 128 k) of MFMA; KH selects af[.][KH*4+ks] statically
template <int KH>
__device__ __forceinline__ void compute_half(const char* buf, int lrow, int lq,
                                             const s16x8 (&af)[2][8],
                                             f32x4 (&acc)[2][8]) {
#pragma unroll
  for (int ks = 0; ks < 4; ++ks) {
    s16x8 bv[8];
#pragma unroll
    for (int n = 0; n < 8; ++n) {
      int col = n * 16 + lrow;
      bv[n] = *(const s16x8*)(buf + (ks >> 1) * 16384 + col * 128 +
                              (((ks & 1) * 64 + lq * 16) ^ ((col & 7) << 4)));
    }
#pragma unroll
    for (int m = 0; m < 2; ++m)
#pragma unroll
      for (int n = 0; n < 8; ++n)
        acc[m][n] = __builtin_amdgcn_mfma_f32_16x16x32_bf16(
            af[m][KH * 4 + ks], bv[n], acc[m][n], 0, 0, 0);
  }
}

// ---------- gram: row-strip blocks, A in registers, B-chunk dbuf ----------
__global__ __launch_bounds__(256, 2) void gram_kernel(
    const short* __restrict__ xbf, const float* __restrict__ sqg,
    const float* __restrict__ alpha_p, float* __restrict__ rpart,
    u32* __restrict__ counter, u32* __restrict__ records) {
  __shared__ __align__(16) char smem[73728];  // 64KB stage/dbuf + 8KB sqall
  float* sqall = (float*)(smem + 65536);

  const int tid = threadIdx.x;
  const int lane = tid & 63;
  const int wid = tid >> 6;
  const int lrow = lane & 15, lq = lane >> 4;

  // XCD-chunk: 512 = 8 * 64 -> 2 batches per XCD (batch L2-resident)
  const int nbid = (blockIdx.x & 7) * 64 + (blockIdx.x >> 3);
  const int b = nbid >> 5;
  const int strip = (nbid >> 1) & 15;
  const int half = nbid & 1;
  const int rowbase = strip * 128;
  const char* xc = (const char*)(xbf + (size_t)b * NS * NE);
  const float alpha = alpha_p[0];
  const float nal = -alpha;
  const float thresh = 17.328680f / alpha;  // 25*ln2/a: exp(w0) rounds to 1.0f

  // stage whole-batch sq (2048 f32) into LDS
  {
    const f32x4* s4 = (const f32x4*)(sqg + b * NS);
    f32x4 a0 = s4[tid * 2], a1 = s4[tid * 2 + 1];
    *(f32x4*)&sqall[tid * 8] = a0;
    *(f32x4*)&sqall[tid * 8 + 4] = a1;
  }
  // stage A strip [128 rows][512B] (inverse-swizzled source, linear dest)
#pragma unroll
  for (int c = 0; c < 16; ++c) {
    int rl = wid * 32 + c * 2 + (lane >> 5);
    int inner = ((lane & 31) * 16) ^ ((rl & 7) << 4);
    gld_lds16(xc + (size_t)(rowbase + rl) * 512 + inner,
              smem + wid * 16384 + c * 1024 + lane * 16);
  }
  __syncthreads();

  // A fragments -> registers (static indices only)
  s16x8 af[2][8];
#pragma unroll
  for (int m = 0; m < 2; ++m) {
    int row = wid * 32 + m * 16 + lrow;
#pragma unroll
    for (int ks = 0; ks < 8; ++ks)
      af[m][ks] = *(const s16x8*)(smem + row * 512 +
                                  ((ks * 64 + lq * 16) ^ ((row & 7) << 4)));
  }
  float rr[2][4], minrr = 3.4e38f;
#pragma unroll
  for (int m = 0; m < 2; ++m)
#pragma unroll
    for (int j = 0; j < 4; ++j) {
      rr[m][j] = sqall[rowbase + wid * 32 + m * 16 + lq * 4 + j];
      minrr = fminf(minrr, rr[m][j]);
    }
  __syncthreads();  // all A reads done before B staging overwrites

  // B chunk staging: [kq(2)][col(128)][128B] layout, 128B col stride
  const int swzl = ((lane & 7) * 16) ^ ((lane >> 3) << 4);
  auto stageB = [&](int bt, int kh, char* buf) {
    const char* base = xc + (size_t)(half * 8 + bt) * 65536 + kh * 256 +
                       (wid >> 1) * 128 + swzl;
    char* dst = buf + wid * 8192 + lane * 16;
#pragma unroll
    for (int i = 0; i < 8; ++i) {
      int colOff = (wid & 1) * 64 + i * 8 + (lane >> 3);
      gld_lds16(base + (size_t)colOff * 512, dst + i * 1024);
    }
  };

  f32x4 acc[2][8];
#pragma unroll
  for (int m = 0; m < 2; ++m)
#pragma unroll
    for (int n = 0; n < 8; ++n) acc[m][n] = (f32x4){0.f, 0.f, 0.f, 0.f};
  float prs[2][4] = {{0.f, 0.f, 0.f, 0.f}, {0.f, 0.f, 0.f, 0.f}};

  stageB(0, 0, smem);
  __syncthreads();

#pragma unroll 1
  for (int bt = 0; bt < 8; ++bt) {
    stageB(bt, 1, smem + 32768);          // prefetch second half of tile bt
    compute_half<0>(smem, lrow, lq, af, acc);
    __syncthreads();                      // drains prefetch; buf0 reads done
    if (bt < 7) stageB(bt + 1, 0, smem);  // prefetch next tile's first half
    compute_half<1>(smem + 32768, lrow, lq, af, acc);

    // ---- epilogue for column tile bt ----
    {
      const int btg = half * 8 + bt;
      float cc[8], mincc = 3.4e38f;
#pragma unroll
      for (int n = 0; n < 8; ++n) {
        cc[n] = sqall[btg * 128 + n * 16 + lrow];
        mincc = fminf(mincc, cc[n]);
      }
      float maxg = -3.4e38f;
#pragma unroll
      for (int m = 0; m < 2; ++m)
#pragma unroll
        for (int n = 0; n < 8; ++n)
#pragma unroll
          for (int j = 0; j < 4; ++j) maxg = fmaxf(maxg, acc[m][n][j]);
      bool fast = (minrr + mincc - 2.f * maxg > thresh);
      if (__all(fast)) {
#pragma unroll
        for (int m = 0; m < 2; ++m)
#pragma unroll
          for (int j = 0; j < 4; ++j) prs[m][j] += 8.0f;
      } else {
#pragma unroll
        for (int m = 0; m < 2; ++m) {
#pragma unroll
          for (int j = 0; j < 4; ++j) {
            float rj = rr[m][j];
#pragma unroll
            for (int n = 0; n < 8; ++n) {
              float d2 = fmaxf(fmaf(-2.f, acc[m][n][j], rj + cc[n]), 0.f);
              float w0 = __expf(nal * d2);  // ==0 for far pairs
              float e = __expf(w0);         // ==1.0f exactly for far pairs
              prs[m][j] += e;
              bool need = d2 < thresh;
              u64 msk = __ballot(need);
              if (msk) {  // wave-aggregated record append
                int leader = __ffsll((long long)msk) - 1;
                u32 base = 0;
                if (lane == leader) base = atomicAdd(counter, (u32)__popcll(msk));
                base = __shfl(base, leader);
                if (need) {
                  u32 idx = base + (u32)__popcll(msk & ((1ull << lane) - 1ull));
                  if (idx < CAP) {
                    int srow = rowbase + wid * 32 + m * 16 + lq * 4 + j;
                    int tcol = btg * 128 + n * 16 + lrow;
                    records[2 * idx] =
                        ((u32)b << 22) | ((u32)srow << 11) | (u32)tcol;
                    records[2 * idx + 1] = __builtin_bit_cast(u32, e);
                  }
                }
              }
            }
          }
        }
      }
#pragma unroll
      for (int m = 0; m < 2; ++m)
#pragma unroll
        for (int n = 0; n < 8; ++n) acc[m][n] = (f32x4){0.f, 0.f, 0.f, 0.f};
    }
    __syncthreads();
  }

  // row partials -> plain stores (reduce over lrow)
#pragma unroll
  for (int m = 0; m < 2; ++m)
#pragma unroll
    for (int j = 0; j < 4; ++j) {
      float v = prs[m][j];
      v += __shfl_xor(v, 1);
      v += __shfl_xor(v, 2);
      v += __shfl_xor(v, 4);
      v += __shfl_xor(v, 8);
      if (lrow == 0)
        rpart[(size_t)(b * 2 + half) * NS + rowbase + wid * 32 + m * 16 +
              lq * 4 + j] = v;
    }
}

// ---------- finale: r -> c[t] (LDS) -> pooled (LDS) -> out; 1 block/batch ----
__global__ __launch_bounds__(512) void finale_kernel(
    const short* __restrict__ xbf, const float* __restrict__ rpart,
    const u32* __restrict__ counter, const u32* __restrict__ records,
    const float* __restrict__ W, const float* __restrict__ bias,
    float* __restrict__ out) {
  __shared__ float rinv_l[NS];       // 8KB
  __shared__ float c_l[NS];          // 8KB
  __shared__ float red[16 * 256];    // 16KB
  __shared__ float pooled_l[NE];     // 1KB
  const int b = blockIdx.x;
  const int tid = threadIdx.x;
  const int lane = tid & 63;
  const int wv = tid >> 6;

  // r = h0 + h1; rinv; sum(1/r)
  float inv_acc = 0.f;
#pragma unroll
  for (int k = 0; k < 4; ++k) {
    int row = k * 512 + tid;
    float r = rpart[(size_t)(2 * b) * NS + row] +
              rpart[(size_t)(2 * b + 1) * NS + row];
    float inv = 1.0f / r;
    rinv_l[row] = inv;
    inv_acc += inv;
  }
#pragma unroll
  for (int off = 32; off; off >>= 1) inv_acc += __shfl_xor(inv_acc, off);
  if (lane == 0) red[wv] = inv_acc;
  __syncthreads();
  float tot = 0.f;
#pragma unroll
  for (int g = 0; g < 8; ++g) tot += red[g];
#pragma unroll
  for (int k = 0; k < 4; ++k) c_l[k * 512 + tid] = tot;
  __syncthreads();

  // sparse corrections: c[t] += (e-1)/r[s]
  u32 cnt = *counter;
  if (cnt > CAP) cnt = CAP;
  for (u32 i = tid; i < cnt; i += 512) {
    u32 meta = records[2 * i];
    if ((int)(meta >> 22) != b) continue;
    float e = __builtin_bit_cast(float, records[2 * i + 1]);
    int s = (meta >> 11) & 2047, t = meta & 2047;
    atomicAdd(&c_l[t], (e - 1.0f) * rinv_l[s]);
  }
  __syncthreads();

  // pooled[e] = (1/S) sum_t c[t] x[t,e]
  const short* xb = xbf + (size_t)b * NS * NE;
  const int e8 = (lane & 31) * 8;
  const int tgrp = wv * 2 + (lane >> 5);  // 16 groups x 128 t
  float acc[8] = {0.f, 0.f, 0.f, 0.f, 0.f, 0.f, 0.f, 0.f};
#pragma unroll 4
  for (int tt = 0; tt < 128; ++tt) {
    int t = tgrp * 128 + tt;
    float cv = c_l[t];
    s16x8 v = *(const s16x8*)(xb + (size_t)t * NE + e8);
#pragma unroll
    for (int j = 0; j < 8; ++j) acc[j] = fmaf(cv, bf16f(v[j]), acc[j]);
  }
#pragma unroll
  for (int j = 0; j < 8; ++j) red[tgrp * 256 + e8 + j] = acc[j];
  __syncthreads();
  if (tid < NE) {
    float s = 0.f;
#pragma unroll
    for (int g = 0; g < 16; ++g) s += red[g * 256 + tid];
    pooled_l[tid] = s * (1.0f / NS);
  }
  __syncthreads();

  // out = pooled @ W^T + bias
  if (tid < NOUT) {
    const f32x4* wr4 = (const f32x4*)(W + (size_t)tid * NE);
    float a = bias[tid];
#pragma unroll 8
    for (int e = 0; e < 64; ++e) {
      f32x4 w4 = wr4[e];
      a += pooled_l[e * 4 + 0] * w4.x + pooled_l[e * 4 + 1] * w4.y +
           pooled_l[e * 4 + 2] * w4.z + pooled_l[e * 4 + 3] * w4.w;
    }
    out[b * NOUT + tid] = a;
  }
}

extern "C" void kernel_launch(void* const* d_in, const int* in_sizes, int n_in,
                              void* d_out, int out_size, void* d_ws, size_t ws_size,
                              hipStream_t stream) {
  const float* x = (const float*)d_in[0];
  const float* alpha = (const float*)d_in[1];
  const float* W = (const float*)d_in[2];
  const float* bias = (const float*)d_in[3];
  float* out = (float*)d_out;

  u32* counter = (u32*)d_ws;                 // 32 u32 (pad)
  float* sq = (float*)(counter + 32);        // NB*NS
  float* rpart = sq + NB * NS;               // 2*NB*NS
  u32* records = (u32*)(rpart + 2 * NB * NS);// 2*CAP
  short* xbf = (short*)(records + 2 * CAP);  // NB*NS*NE bf16

  hipMemsetAsync(counter, 0, 128, stream);
  prep_kernel<<<NB * NS / 4, 256, 0, stream>>>(x, xbf, sq);
  gram_kernel<<<512, 256, 0, stream>>>(xbf, sq, alpha, rpart, counter, records);
  finale_kernel<<<NB, 512, 0, stream>>>(xbf, rpart, counter, records, W, bias,
                                        out);
}

// Round 7
// 157.241 us; speedup vs baseline: 1.4779x; 1.4779x over previous
//
#include <hip/hip_runtime.h>
#include <hip/hip_bf16.h>

#define NB 16
#define NS 2048
#define NE 256
#define NOUT 256
#define CAP 49152
#define RCAP 384  // per-block LDS record capacity (diag strip needs 128)

typedef __attribute__((ext_vector_type(4))) float f32x4;
typedef __attribute__((ext_vector_type(8))) short s16x8;
typedef __attribute__((ext_vector_type(4))) short s16x4;
typedef unsigned int u32;
typedef unsigned long long u64;

__device__ __forceinline__ short bf16rn(float f) {
  unsigned u = __builtin_bit_cast(unsigned, f);
  u += 0x7FFFu + ((u >> 16) & 1u);
  return (short)(u >> 16);
}
__device__ __forceinline__ float bf16f(short s) {
  unsigned u = ((unsigned)(unsigned short)s) << 16;
  return __builtin_bit_cast(float, u);
}
__device__ __forceinline__ void gld_lds16(const void* g, void* l) {
  __builtin_amdgcn_global_load_lds(
      (const __attribute__((address_space(1))) u32*)g,
      (__attribute__((address_space(3))) u32*)l, 16, 0, 0);
}

// ---------- prep: x f32 -> xbf bf16 + sq; block 0 zeroes counter ----------
__global__ __launch_bounds__(256) void prep_kernel(const float* __restrict__ x,
                                                   short* __restrict__ xbf,
                                                   float* __restrict__ sq,
                                                   u32* __restrict__ counter) {
  if (blockIdx.x == 0 && threadIdx.x == 0) *counter = 0u;
  int row = blockIdx.x * 4 + (threadIdx.x >> 6);
  int lane = threadIdx.x & 63;
  f32x4 v = *(const f32x4*)(x + (size_t)row * NE + lane * 4);
  s16x4 p;
  p[0] = bf16rn(v.x); p[1] = bf16rn(v.y); p[2] = bf16rn(v.z); p[3] = bf16rn(v.w);
  *(s16x4*)(xbf + (size_t)row * NE + lane * 4) = p;
  float s = v.x * v.x + v.y * v.y + v.z * v.z + v.w * v.w;
#pragma unroll
  for (int off = 32; off; off >>= 1) s += __shfl_xor(s, off);
  if (lane == 0) sq[row] = s;
}

// one half-chunk (128 cols x 128 k) of MFMA; KH selects af[.][KH*4+ks] statically
template <int KH>
__device__ __forceinline__ void compute_half(const char* buf, int lrow, int lq,
                                             const s16x8 (&af)[2][8],
                                             f32x4 (&acc)[2][8]) {
#pragma unroll
  for (int ks = 0; ks < 4; ++ks) {
    s16x8 bv[8];
#pragma unroll
    for (int n = 0; n < 8; ++n) {
      int col = n * 16 + lrow;
      bv[n] = *(const s16x8*)(buf + (ks >> 1) * 16384 + col * 128 +
                              (((ks & 1) * 64 + lq * 16) ^ ((col & 7) << 4)));
    }
#pragma unroll
    for (int m = 0; m < 2; ++m)
#pragma unroll
      for (int n = 0; n < 8; ++n)
        acc[m][n] = __builtin_amdgcn_mfma_f32_16x16x32_bf16(
            af[m][KH * 4 + ks], bv[n], acc[m][n], 0, 0, 0);
  }
}

// ---------- gram: row-strip blocks, A in registers, B-chunk dbuf ----------
__global__ __launch_bounds__(256, 2) void gram_kernel(
    const short* __restrict__ xbf, const float* __restrict__ sqg,
    const float* __restrict__ alpha_p, float* __restrict__ rpart,
    u32* __restrict__ counter, u32* __restrict__ records) {
  __shared__ __align__(16) char smem[73728];  // 64KB stage/dbuf + 8KB sqall
  __shared__ u32 rec_meta[RCAP];
  __shared__ float rec_e[RCAP];
  __shared__ u32 rec_cnt, rec_gbase;
  float* sqall = (float*)(smem + 65536);

  const int tid = threadIdx.x;
  const int lane = tid & 63;
  const int wid = tid >> 6;
  const int lrow = lane & 15, lq = lane >> 4;

  // XCD-chunk: 512 = 8 * 64 -> 2 batches per XCD (batch L2-resident)
  const int nbid = (blockIdx.x & 7) * 64 + (blockIdx.x >> 3);
  const int b = nbid >> 5;
  const int strip = (nbid >> 1) & 15;
  const int half = nbid & 1;
  const int rowbase = strip * 128;
  const char* xc = (const char*)(xbf + (size_t)b * NS * NE);
  const float alpha = alpha_p[0];
  const float nal = -alpha;
  const float thresh = 17.328680f / alpha;  // 25*ln2/a: exp(w0) rounds to 1.0f

  if (tid == 0) rec_cnt = 0u;

  // stage whole-batch sq (2048 f32) into LDS
  {
    const f32x4* s4 = (const f32x4*)(sqg + b * NS);
    f32x4 a0 = s4[tid * 2], a1 = s4[tid * 2 + 1];
    *(f32x4*)&sqall[tid * 8] = a0;
    *(f32x4*)&sqall[tid * 8 + 4] = a1;
  }
  // stage A strip [128 rows][512B] (inverse-swizzled source, linear dest)
#pragma unroll
  for (int c = 0; c < 16; ++c) {
    int rl = wid * 32 + c * 2 + (lane >> 5);
    int inner = ((lane & 31) * 16) ^ ((rl & 7) << 4);
    gld_lds16(xc + (size_t)(rowbase + rl) * 512 + inner,
              smem + wid * 16384 + c * 1024 + lane * 16);
  }
  __syncthreads();

  // A fragments -> registers (static indices only)
  s16x8 af[2][8];
#pragma unroll
  for (int m = 0; m < 2; ++m) {
    int row = wid * 32 + m * 16 + lrow;
#pragma unroll
    for (int ks = 0; ks < 8; ++ks)
      af[m][ks] = *(const s16x8*)(smem + row * 512 +
                                  ((ks * 64 + lq * 16) ^ ((row & 7) << 4)));
  }
  float rr[2][4], minrr = 3.4e38f;
#pragma unroll
  for (int m = 0; m < 2; ++m)
#pragma unroll
    for (int j = 0; j < 4; ++j) {
      rr[m][j] = sqall[rowbase + wid * 32 + m * 16 + lq * 4 + j];
      minrr = fminf(minrr, rr[m][j]);
    }
  __syncthreads();  // all A reads done before B staging overwrites

  // B chunk staging: [kq(2)][col(128)][128B] layout, 128B col stride
  const int swzl = ((lane & 7) * 16) ^ ((lane >> 3) << 4);
  auto stageB = [&](int bt, int kh, char* buf) {
    const char* base = xc + (size_t)(half * 8 + bt) * 65536 + kh * 256 +
                       (wid >> 1) * 128 + swzl;
    char* dst = buf + wid * 8192 + lane * 16;
#pragma unroll
    for (int i = 0; i < 8; ++i) {
      int colOff = (wid & 1) * 64 + i * 8 + (lane >> 3);
      gld_lds16(base + (size_t)colOff * 512, dst + i * 1024);
    }
  };

  f32x4 acc[2][8];
#pragma unroll
  for (int m = 0; m < 2; ++m)
#pragma unroll
    for (int n = 0; n < 8; ++n) acc[m][n] = (f32x4){0.f, 0.f, 0.f, 0.f};
  float prs[2][4] = {{0.f, 0.f, 0.f, 0.f}, {0.f, 0.f, 0.f, 0.f}};

  stageB(0, 0, smem);
  __syncthreads();

#pragma unroll 1
  for (int bt = 0; bt < 8; ++bt) {
    stageB(bt, 1, smem + 32768);          // prefetch second half of tile bt
    compute_half<0>(smem, lrow, lq, af, acc);
    __syncthreads();                      // drains prefetch; buf0 reads done
    if (bt < 7) stageB(bt + 1, 0, smem);  // prefetch next tile's first half
    compute_half<1>(smem + 32768, lrow, lq, af, acc);

    // ---- epilogue for column tile bt ----
    {
      const int btg = half * 8 + bt;
      float cc[8], mincc = 3.4e38f;
#pragma unroll
      for (int n = 0; n < 8; ++n) {
        cc[n] = sqall[btg * 128 + n * 16 + lrow];
        mincc = fminf(mincc, cc[n]);
      }
      float maxg = -3.4e38f;
#pragma unroll
      for (int m = 0; m < 2; ++m)
#pragma unroll
        for (int n = 0; n < 8; ++n)
#pragma unroll
          for (int j = 0; j < 4; ++j) maxg = fmaxf(maxg, acc[m][n][j]);
      bool fast = (minrr + mincc - 2.f * maxg > thresh);
      if (__all(fast)) {
#pragma unroll
        for (int m = 0; m < 2; ++m)
#pragma unroll
          for (int j = 0; j < 4; ++j) prs[m][j] += 8.0f;
      } else {
#pragma unroll
        for (int m = 0; m < 2; ++m) {
#pragma unroll
          for (int j = 0; j < 4; ++j) {
            float rj = rr[m][j];
#pragma unroll
            for (int n = 0; n < 8; ++n) {
              float d2 = fmaxf(fmaf(-2.f, acc[m][n][j], rj + cc[n]), 0.f);
              float w0 = __expf(nal * d2);  // ==0 for far pairs
              float e = __expf(w0);         // ==1.0f exactly for far pairs
              prs[m][j] += e;
              if (d2 < thresh) {  // block-local record append (LDS atomic)
                u32 idx = atomicAdd(&rec_cnt, 1u);
                if (idx < RCAP) {
                  int srow = rowbase + wid * 32 + m * 16 + lq * 4 + j;
                  int tcol = btg * 128 + n * 16 + lrow;
                  rec_meta[idx] = ((u32)srow << 11) | (u32)tcol;
                  rec_e[idx] = e;
                }
              }
            }
          }
        }
      }
#pragma unroll
      for (int m = 0; m < 2; ++m)
#pragma unroll
        for (int n = 0; n < 8; ++n) acc[m][n] = (f32x4){0.f, 0.f, 0.f, 0.f};
    }
    __syncthreads();
  }

  // row partials -> plain stores (reduce over lrow)
#pragma unroll
  for (int m = 0; m < 2; ++m)
#pragma unroll
    for (int j = 0; j < 4; ++j) {
      float v = prs[m][j];
      v += __shfl_xor(v, 1);
      v += __shfl_xor(v, 2);
      v += __shfl_xor(v, 4);
      v += __shfl_xor(v, 8);
      if (lrow == 0)
        rpart[(size_t)(b * 2 + half) * NS + rowbase + wid * 32 + m * 16 +
              lq * 4 + j] = v;
    }

  // flush block-local records with ONE global atomic
  __syncthreads();
  u32 cnt = rec_cnt;
  if (cnt > RCAP) cnt = RCAP;
  if (cnt) {
    if (tid == 0) rec_gbase = atomicAdd(counter, cnt);
    __syncthreads();
    u32 gb = rec_gbase;
    for (u32 i = tid; i < cnt; i += 256) {
      u32 g = gb + i;
      if (g < CAP) {
        records[2 * g] = ((u32)b << 22) | rec_meta[i];
        records[2 * g + 1] = __builtin_bit_cast(u32, rec_e[i]);
      }
    }
  }
}

// ---------- finale: r -> c[t] (LDS) -> pooled (LDS) -> out; 1 block/batch ----
__global__ __launch_bounds__(512) void finale_kernel(
    const short* __restrict__ xbf, const float* __restrict__ rpart,
    const u32* __restrict__ counter, const u32* __restrict__ records,
    const float* __restrict__ W, const float* __restrict__ bias,
    float* __restrict__ out) {
  __shared__ float rinv_l[NS];       // 8KB
  __shared__ float c_l[NS];          // 8KB
  __shared__ float red[16 * 256];    // 16KB
  __shared__ float pooled_l[NE];     // 1KB
  const int b = blockIdx.x;
  const int tid = threadIdx.x;
  const int lane = tid & 63;
  const int wv = tid >> 6;

  // r = h0 + h1; rinv; sum(1/r)
  float inv_acc = 0.f;
#pragma unroll
  for (int k = 0; k < 4; ++k) {
    int row = k * 512 + tid;
    float r = rpart[(size_t)(2 * b) * NS + row] +
              rpart[(size_t)(2 * b + 1) * NS + row];
    float inv = 1.0f / r;
    rinv_l[row] = inv;
    inv_acc += inv;
  }
#pragma unroll
  for (int off = 32; off; off >>= 1) inv_acc += __shfl_xor(inv_acc, off);
  if (lane == 0) red[wv] = inv_acc;
  __syncthreads();
  float tot = 0.f;
#pragma unroll
  for (int g = 0; g < 8; ++g) tot += red[g];
#pragma unroll
  for (int k = 0; k < 4; ++k) c_l[k * 512 + tid] = tot;
  __syncthreads();

  // sparse corrections: c[t] += (e-1)/r[s]
  u32 cnt = *counter;
  if (cnt > CAP) cnt = CAP;
  for (u32 i = tid; i < cnt; i += 512) {
    u32 meta = records[2 * i];
    if ((int)(meta >> 22) != b) continue;
    float e = __builtin_bit_cast(float, records[2 * i + 1]);
    int s = (meta >> 11) & 2047, t = meta & 2047;
    atomicAdd(&c_l[t], (e - 1.0f) * rinv_l[s]);
  }
  __syncthreads();

  // pooled[e] = (1/S) sum_t c[t] x[t,e]
  const short* xb = xbf + (size_t)b * NS * NE;
  const int e8 = (lane & 31) * 8;
  const int tgrp = wv * 2 + (lane >> 5);  // 16 groups x 128 t
  float acc[8] = {0.f, 0.f, 0.f, 0.f, 0.f, 0.f, 0.f, 0.f};
#pragma unroll 4
  for (int tt = 0; tt < 128; ++tt) {
    int t = tgrp * 128 + tt;
    float cv = c_l[t];
    s16x8 v = *(const s16x8*)(xb + (size_t)t * NE + e8);
#pragma unroll
    for (int j = 0; j < 8; ++j) acc[j] = fmaf(cv, bf16f(v[j]), acc[j]);
  }
#pragma unroll
  for (int j = 0; j < 8; ++j) red[tgrp * 256 + e8 + j] = acc[j];
  __syncthreads();
  if (tid < NE) {
    float s = 0.f;
#pragma unroll
    for (int g = 0; g < 16; ++g) s += red[g * 256 + tid];
    pooled_l[tid] = s * (1.0f / NS);
  }
  __syncthreads();

  // out = pooled @ W^T + bias
  if (tid < NOUT) {
    const f32x4* wr4 = (const f32x4*)(W + (size_t)tid * NE);
    float a = bias[tid];
#pragma unroll 8
    for (int e = 0; e < 64; ++e) {
      f32x4 w4 = wr4[e];
      a += pooled_l[e * 4 + 0] * w4.x + pooled_l[e * 4 + 1] * w4.y +
           pooled_l[e * 4 + 2] * w4.z + pooled_l[e * 4 + 3] * w4.w;
    }
    out[b * NOUT + tid] = a;
  }
}

extern "C" void kernel_launch(void* const* d_in, const int* in_sizes, int n_in,
                              void* d_out, int out_size, void* d_ws, size_t ws_size,
                              hipStream_t stream) {
  const float* x = (const float*)d_in[0];
  const float* alpha = (const float*)d_in[1];
  const float* W = (const float*)d_in[2];
  const float* bias = (const float*)d_in[3];
  float* out = (float*)d_out;

  u32* counter = (u32*)d_ws;                 // 32 u32 (pad)
  float* sq = (float*)(counter + 32);        // NB*NS
  float* rpart = sq + NB * NS;               // 2*NB*NS
  u32* records = (u32*)(rpart + 2 * NB * NS);// 2*CAP
  short* xbf = (short*)(records + 2 * CAP);  // NB*NS*NE bf16

  prep_kernel<<<NB * NS / 4, 256, 0, stream>>>(x, xbf, sq, counter);
  gram_kernel<<<512, 256, 0, stream>>>(xbf, sq, alpha, rpart, counter, records);
  finale_kernel<<<NB, 512, 0, stream>>>(xbf, rpart, counter, records, W, bias,
                                        out);
}

// Round 8
// 154.913 us; speedup vs baseline: 1.5001x; 1.0150x over previous
//
#include <hip/hip_runtime.h>
#include <hip/hip_bf16.h>

#define NB 16
#define NS 2048
#define NE 256
#define NOUT 256
#define CAP 49152
#define RCAP 384  // per-block LDS record capacity (diag quad-block needs ~140)

typedef __attribute__((ext_vector_type(4))) float f32x4;
typedef __attribute__((ext_vector_type(8))) short s16x8;
typedef __attribute__((ext_vector_type(4))) short s16x4;
typedef unsigned int u32;
typedef unsigned long long u64;

__device__ __forceinline__ short bf16rn(float f) {
  unsigned u = __builtin_bit_cast(unsigned, f);
  u += 0x7FFFu + ((u >> 16) & 1u);
  return (short)(u >> 16);
}
__device__ __forceinline__ float bf16f(short s) {
  unsigned u = ((unsigned)(unsigned short)s) << 16;
  return __builtin_bit_cast(float, u);
}
__device__ __forceinline__ void gld_lds16(const void* g, void* l) {
  __builtin_amdgcn_global_load_lds(
      (const __attribute__((address_space(1))) u32*)g,
      (__attribute__((address_space(3))) u32*)l, 16, 0, 0);
}

// ---------- prep: x f32 -> xbf bf16 + sq; block 0 zeroes counter ----------
__global__ __launch_bounds__(256) void prep_kernel(const float* __restrict__ x,
                                                   short* __restrict__ xbf,
                                                   float* __restrict__ sq,
                                                   u32* __restrict__ counter) {
  if (blockIdx.x == 0 && threadIdx.x == 0) *counter = 0u;
  int row = blockIdx.x * 4 + (threadIdx.x >> 6);
  int lane = threadIdx.x & 63;
  f32x4 v = *(const f32x4*)(x + (size_t)row * NE + lane * 4);
  s16x4 p;
  p[0] = bf16rn(v.x); p[1] = bf16rn(v.y); p[2] = bf16rn(v.z); p[3] = bf16rn(v.w);
  *(s16x4*)(xbf + (size_t)row * NE + lane * 4) = p;
  float s = v.x * v.x + v.y * v.y + v.z * v.z + v.w * v.w;
#pragma unroll
  for (int off = 32; off; off >>= 1) s += __shfl_xor(s, off);
  if (lane == 0) sq[row] = s;
}

// ---------- gram: 1024 blocks = b(16) x strip(16) x quad(4) ----------
// Each block: rows [strip*128,+128) (A frags in VGPRs, K=256), cols
// [quad*512,+512) as 4 bt tiles of 128 cols; B staged in 16KB chunks, dbuf.
__global__ __launch_bounds__(256, 2) void gram_kernel(
    const short* __restrict__ xbf, const float* __restrict__ sqg,
    const float* __restrict__ alpha_p, float* __restrict__ rpart,
    u32* __restrict__ counter, u32* __restrict__ records) {
  __shared__ __align__(16) char smem[32768];  // B dbuf: 2 x 16KB
  __shared__ u32 rec_meta[RCAP];
  __shared__ float rec_e[RCAP];
  __shared__ u32 rec_cnt, rec_gbase;

  const int tid = threadIdx.x;
  const int lane = tid & 63;
  const int wid = tid >> 6;
  const int lrow = lane & 15, lq = lane >> 4;

  // XCD-chunk: 1024 = 8 * 128 -> 2 batches per XCD (B re-reads L2-resident)
  const int nbid = (blockIdx.x & 7) * 128 + (blockIdx.x >> 3);
  const int b = nbid >> 6;
  const int strip = (nbid >> 2) & 15;
  const int quad = nbid & 3;
  const int rowbase = strip * 128;
  const int colbase = quad * 512;
  const char* xc = (const char*)(xbf + (size_t)b * NS * NE);
  const float alpha = alpha_p[0];
  const float nal = -alpha;
  const float thresh = 17.328680f / alpha;  // 25*ln2/a: exp(w0) rounds to 1.0f

  if (tid == 0) rec_cnt = 0u;

  // A fragments: direct global -> VGPR (rows linear 512B, no swizzle needed)
  s16x8 af[2][8];
#pragma unroll
  for (int m = 0; m < 2; ++m) {
    const char* arow = xc + (size_t)(rowbase + wid * 32 + m * 16 + lrow) * 512;
#pragma unroll
    for (int ks = 0; ks < 8; ++ks)
      af[m][ks] = *(const s16x8*)(arow + ks * 64 + lq * 16);
  }
  float rr[2][4], minrr = 3.4e38f;
#pragma unroll
  for (int m = 0; m < 2; ++m)
#pragma unroll
    for (int j = 0; j < 4; ++j) {
      rr[m][j] = sqg[b * NS + rowbase + wid * 32 + m * 16 + lq * 4 + j];
      minrr = fminf(minrr, rr[m][j]);
    }

  // B chunk staging: chunk = [col(128)][128B] = 16KB, k-range 64 per chunk
  const int swzl = ((lane & 7) * 16) ^ ((lane >> 3) << 4);
  auto stageB = [&](int bt, int c, char* buf) {
    const char* base = xc + (size_t)(colbase + bt * 128 + wid * 32 + (lane >> 3)) * 512 +
                       c * 128 + swzl;
    char* dst = buf + wid * 4096 + lane * 16;
#pragma unroll
    for (int i = 0; i < 4; ++i) {
      gld_lds16(base + (size_t)(i * 8) * 512, dst + i * 1024);
    }
  };

  f32x4 acc[2][8];
#pragma unroll
  for (int m = 0; m < 2; ++m)
#pragma unroll
    for (int n = 0; n < 8; ++n) acc[m][n] = (f32x4){0.f, 0.f, 0.f, 0.f};
  float prs[2][4] = {{0.f, 0.f, 0.f, 0.f}, {0.f, 0.f, 0.f, 0.f}};

  stageB(0, 0, smem);
  __syncthreads();

#pragma unroll 1
  for (int bt = 0; bt < 4; ++bt) {
#pragma unroll
    for (int c = 0; c < 4; ++c) {  // c static: af index + buffer parity static
      // prefetch next chunk into the other buffer
      if (!(bt == 3 && c == 3)) {
        int btn = (c == 3) ? bt + 1 : bt;
        stageB(btn, (c + 1) & 3, smem + (((c + 1) & 1) ? 16384 : 0));
      }
      const char* buf = smem + ((c & 1) ? 16384 : 0);
#pragma unroll
      for (int ks = 0; ks < 2; ++ks) {
        s16x8 bv[8];
#pragma unroll
        for (int n = 0; n < 8; ++n) {
          int col = n * 16 + lrow;
          bv[n] = *(const s16x8*)(buf + col * 128 +
                                  ((ks * 64 + lq * 16) ^ ((col & 7) << 4)));
        }
#pragma unroll
        for (int m = 0; m < 2; ++m)
#pragma unroll
          for (int n = 0; n < 8; ++n)
            acc[m][n] = __builtin_amdgcn_mfma_f32_16x16x32_bf16(
                af[m][c * 2 + ks], bv[n], acc[m][n], 0, 0, 0);
      }

      if (c == 3) {
        // ---- epilogue for column tile bt ----
        const int btg = quad * 4 + bt;
        float cc[8], mincc = 3.4e38f;
#pragma unroll
        for (int n = 0; n < 8; ++n) {
          cc[n] = sqg[b * NS + btg * 128 + n * 16 + lrow];
          mincc = fminf(mincc, cc[n]);
        }
        float maxg = -3.4e38f;
#pragma unroll
        for (int m = 0; m < 2; ++m)
#pragma unroll
          for (int n = 0; n < 8; ++n)
#pragma unroll
            for (int j = 0; j < 4; ++j) maxg = fmaxf(maxg, acc[m][n][j]);
        bool fast = (minrr + mincc - 2.f * maxg > thresh);
        if (__all(fast)) {
#pragma unroll
          for (int m = 0; m < 2; ++m)
#pragma unroll
            for (int j = 0; j < 4; ++j) prs[m][j] += 8.0f;
        } else {
#pragma unroll
          for (int m = 0; m < 2; ++m) {
#pragma unroll
            for (int j = 0; j < 4; ++j) {
              float rj = rr[m][j];
#pragma unroll
              for (int n = 0; n < 8; ++n) {
                float d2 = fmaxf(fmaf(-2.f, acc[m][n][j], rj + cc[n]), 0.f);
                float w0 = __expf(nal * d2);  // ==0 for far pairs
                float e = __expf(w0);         // ==1.0f exactly for far pairs
                prs[m][j] += e;
                if (d2 < thresh) {  // block-local record append (LDS atomic)
                  u32 idx = atomicAdd(&rec_cnt, 1u);
                  if (idx < RCAP) {
                    int srow = rowbase + wid * 32 + m * 16 + lq * 4 + j;
                    int tcol = btg * 128 + n * 16 + lrow;
                    rec_meta[idx] = ((u32)srow << 11) | (u32)tcol;
                    rec_e[idx] = e;
                  }
                }
              }
            }
          }
        }
#pragma unroll
        for (int m = 0; m < 2; ++m)
#pragma unroll
          for (int n = 0; n < 8; ++n) acc[m][n] = (f32x4){0.f, 0.f, 0.f, 0.f};
      }
      __syncthreads();  // drains prefetch vmcnt + protects dbuf swap
    }
  }

  // row partials -> plain stores, one slot per (b,quad)
#pragma unroll
  for (int m = 0; m < 2; ++m)
#pragma unroll
    for (int j = 0; j < 4; ++j) {
      float v = prs[m][j];
      v += __shfl_xor(v, 1);
      v += __shfl_xor(v, 2);
      v += __shfl_xor(v, 4);
      v += __shfl_xor(v, 8);
      if (lrow == 0)
        rpart[(size_t)(b * 4 + quad) * NS + rowbase + wid * 32 + m * 16 +
              lq * 4 + j] = v;
    }

  // flush block-local records with ONE global atomic
  u32 cnt = rec_cnt;
  if (cnt > RCAP) cnt = RCAP;
  if (cnt) {
    if (tid == 0) rec_gbase = atomicAdd(counter, cnt);
    __syncthreads();
    u32 gb = rec_gbase;
    for (u32 i = tid; i < cnt; i += 256) {
      u32 g = gb + i;
      if (g < CAP) {
        records[2 * g] = ((u32)b << 22) | rec_meta[i];
        records[2 * g + 1] = __builtin_bit_cast(u32, rec_e[i]);
      }
    }
  }
}

// ---------- finale: r -> c[t] (LDS) -> pooled (LDS) -> out; 1024 thr/batch ----
__global__ __launch_bounds__(1024) void finale_kernel(
    const short* __restrict__ xbf, const float* __restrict__ rpart,
    const u32* __restrict__ counter, const u32* __restrict__ records,
    const float* __restrict__ W, const float* __restrict__ bias,
    float* __restrict__ out) {
  __shared__ float rinv_l[NS];       // 8KB
  __shared__ float c_l[NS];          // 8KB
  __shared__ float red[32 * 256];    // 32KB
  __shared__ float pooled_l[NE];     // 1KB
  const int b = blockIdx.x;
  const int tid = threadIdx.x;
  const int lane = tid & 63;
  const int wv = tid >> 6;

  // r = sum of 4 quad partials; rinv; sum(1/r)
  float inv_acc = 0.f;
#pragma unroll
  for (int k = 0; k < 2; ++k) {
    int row = k * 1024 + tid;
    float r = rpart[(size_t)(4 * b + 0) * NS + row] +
              rpart[(size_t)(4 * b + 1) * NS + row] +
              rpart[(size_t)(4 * b + 2) * NS + row] +
              rpart[(size_t)(4 * b + 3) * NS + row];
    float inv = 1.0f / r;
    rinv_l[row] = inv;
    inv_acc += inv;
  }
#pragma unroll
  for (int off = 32; off; off >>= 1) inv_acc += __shfl_xor(inv_acc, off);
  if (lane == 0) red[wv] = inv_acc;
  __syncthreads();
  float tot = 0.f;
#pragma unroll
  for (int g = 0; g < 16; ++g) tot += red[g];
#pragma unroll
  for (int k = 0; k < 2; ++k) c_l[k * 1024 + tid] = tot;
  __syncthreads();

  // sparse corrections: c[t] += (e-1)/r[s]
  u32 cnt = *counter;
  if (cnt > CAP) cnt = CAP;
  for (u32 i = tid; i < cnt; i += 1024) {
    u32 meta = records[2 * i];
    if ((int)(meta >> 22) != b) continue;
    float e = __builtin_bit_cast(float, records[2 * i + 1]);
    int s = (meta >> 11) & 2047, t = meta & 2047;
    atomicAdd(&c_l[t], (e - 1.0f) * rinv_l[s]);
  }
  __syncthreads();

  // pooled[e] = (1/S) sum_t c[t] x[t,e]  (32 t-groups x 64 t each)
  const short* xb = xbf + (size_t)b * NS * NE;
  const int e8 = (lane & 31) * 8;
  const int tgrp = wv * 2 + (lane >> 5);
  float acc[8] = {0.f, 0.f, 0.f, 0.f, 0.f, 0.f, 0.f, 0.f};
#pragma unroll 4
  for (int tt = 0; tt < 64; ++tt) {
    int t = tgrp * 64 + tt;
    float cv = c_l[t];
    s16x8 v = *(const s16x8*)(xb + (size_t)t * NE + e8);
#pragma unroll
    for (int j = 0; j < 8; ++j) acc[j] = fmaf(cv, bf16f(v[j]), acc[j]);
  }
#pragma unroll
  for (int j = 0; j < 8; ++j) red[tgrp * 256 + e8 + j] = acc[j];
  __syncthreads();
  if (tid < NE) {
    float s = 0.f;
#pragma unroll
    for (int g = 0; g < 32; ++g) s += red[g * 256 + tid];
    pooled_l[tid] = s * (1.0f / NS);
  }
  __syncthreads();

  // out = pooled @ W^T + bias
  if (tid < NOUT) {
    const f32x4* wr4 = (const f32x4*)(W + (size_t)tid * NE);
    float a = bias[tid];
#pragma unroll 8
    for (int e = 0; e < 64; ++e) {
      f32x4 w4 = wr4[e];
      a += pooled_l[e * 4 + 0] * w4.x + pooled_l[e * 4 + 1] * w4.y +
           pooled_l[e * 4 + 2] * w4.z + pooled_l[e * 4 + 3] * w4.w;
    }
    out[b * NOUT + tid] = a;
  }
}

extern "C" void kernel_launch(void* const* d_in, const int* in_sizes, int n_in,
                              void* d_out, int out_size, void* d_ws, size_t ws_size,
                              hipStream_t stream) {
  const float* x = (const float*)d_in[0];
  const float* alpha = (const float*)d_in[1];
  const float* W = (const float*)d_in[2];
  const float* bias = (const float*)d_in[3];
  float* out = (float*)d_out;

  u32* counter = (u32*)d_ws;                 // 32 u32 (pad)
  float* sq = (float*)(counter + 32);        // NB*NS
  float* rpart = sq + NB * NS;               // 4*NB*NS
  u32* records = (u32*)(rpart + 4 * NB * NS);// 2*CAP
  short* xbf = (short*)(records + 2 * CAP);  // NB*NS*NE bf16

  prep_kernel<<<NB * NS / 4, 256, 0, stream>>>(x, xbf, sq, counter);
  gram_kernel<<<1024, 256, 0, stream>>>(xbf, sq, alpha, rpart, counter, records);
  finale_kernel<<<NB, 1024, 0, stream>>>(xbf, rpart, counter, records, W, bias,
                                         out);
}